// Round 3
// baseline (294.888 us; speedup 1.0000x reference)
//
#include <hip/hip_runtime.h>
#include <climits>

// StreamingRhythmProjector: B=4096 rows x U=2048 units.
// ONE WAVE PER ROW: 64 threads x 32 elems. Zero barriers, zero LDS —
// all reductions are wave-synchronous __shfl_xor butterflies. Per-row
// scalars are wave-uniform s_loads issued at entry (latency hidden).
// State kept in regs: sr (masked speech_raw) + src (raw anchor) = 64 VGPRs;
// mask derived as (sr != 0); p,b re-read in pass 2 (L2/L3-warm).

constexpr int UNITS = 2048;
constexpr int BLOCK = 64;            // one wave
constexpr int CH = UNITS / (BLOCK * 4);  // 8 float4 chunks per thread

static __device__ __forceinline__ float bflySum(float v) {
#pragma unroll
  for (int m = 1; m < 64; m <<= 1) v += __shfl_xor(v, m, 64);
  return v;  // result identical on all 64 lanes
}
static __device__ __forceinline__ int bflyMin(int v) {
#pragma unroll
  for (int m = 1; m < 64; m <<= 1) v = min(v, __shfl_xor(v, m, 64));
  return v;
}

__global__ __launch_bounds__(BLOCK, 4) void rhythm_kernel(
    const float* __restrict__ dur_anchor,    // [B,U]
    const float* __restrict__ unit_mask,     // [B,U] prefix mask (0/1)
    const float* __restrict__ speech_budget, // [B]
    const float* __restrict__ pause_budget,  // [B]
    const float* __restrict__ dur_logratio,  // [B,U]
    const float* __restrict__ pause_weight,  // [B,U]
    const float* __restrict__ boundary,      // [B,U]
    const float* __restrict__ phase_ptr,     // [B]
    const float* __restrict__ backlog,       // [B]
    const float* __restrict__ clock_delta,   // [B]
    const int*   __restrict__ commit_front,  // [B]
    const int*   __restrict__ open_run,      // [B,U]
    float* __restrict__ out,                 // f32, 3*B*U + 4*B
    int B) {
  const int row = blockIdx.x;
  const int t = threadIdx.x;
  const size_t base = (size_t)row * UNITS;

  // wave-uniform per-row scalars -> s_loads, issued before the vector stream
  const int prev = commit_front[row];
  const float sb = speech_budget[row];
  const float pb = pause_budget[row];
  const float pp = phase_ptr[row];
  const float bl = backlog[row];
  const float cd = clock_delta[row];

  // ---- pass 1: stream all 6 arrays once; keep sr+src in registers ----
  float sv_sr[CH * 4];   // masked speech_raw (0 where mask==0, else >= 1)
  float sv_src[CH * 4];  // raw dur_anchor_src
  float sum_sr = 0.f, sum_sc = 0.f, sum_m = 0.f;
  int min_open = INT_MAX;

#pragma unroll
  for (int c = 0; c < CH; ++c) {
    const int e0 = c * (BLOCK * 4) + 4 * t;
    const float4 a4 = *(const float4*)(dur_anchor   + base + e0);
    const float4 m4 = *(const float4*)(unit_mask    + base + e0);
    const float4 l4 = *(const float4*)(dur_logratio + base + e0);
    const float4 p4 = *(const float4*)(pause_weight + base + e0);
    const float4 b4 = *(const float4*)(boundary     + base + e0);
    const int4   o4 = *(const int4*)(open_run       + base + e0);
    const float av[4] = {a4.x, a4.y, a4.z, a4.w};
    const float mv[4] = {m4.x, m4.y, m4.z, m4.w};
    const float lv[4] = {l4.x, l4.y, l4.z, l4.w};
    const float pv[4] = {p4.x, p4.y, p4.z, p4.w};
    const float bv[4] = {b4.x, b4.y, b4.z, b4.w};
    const int   ov[4] = {o4.x, o4.y, o4.z, o4.w};
#pragma unroll
    for (int j = 0; j < 4; ++j) {
      const int k = c * 4 + j;
      const float m = mv[j];
      const float a = fmaxf(av[j], 1.0f);                      // MIN_SPEECH_FRAMES
      const float bse = a * __expf(lv[j]);
      const float sr = fmaxf(fminf(bse, 3.0f * a), 1.0f) * m;  // MAX_SPEECH_EXPAND
      const float sc = fmaxf(pv[j], 0.0f) * (0.5f + bv[j]) * m;
      sv_sr[k] = sr;
      sv_src[k] = av[j];
      sum_sr += sr;
      sum_sc += sc;
      sum_m += m;
      // prefix mask => (idx < visible) <=> m == 1
      if (ov[j] > 0 && m > 0.5f) min_open = min(min_open, e0 + j);
    }
  }

  // ---- wave reduction 1 (butterfly: every lane gets the result) ----
  const float ts = bflySum(sum_sr);
  const float tc = bflySum(sum_sc);
  const float tm = bflySum(sum_m);
  const int mo = bflyMin(min_open);

  // ---- commit frontier + scales, computed uniformly on all lanes ----
  const int visible = (int)(tm + 0.5f);               // exact: integer-valued f32
  const int closed = (mo == INT_MAX) ? visible : mo;
  const int relcap = max(visible - 2, 0);             // TAIL_HOLD_UNITS
  int cand = min(relcap, closed);
  const int bidx = min(max(cand - 1, 0), UNITS - 1);
  const float bval = boundary[base + bidx];           // uniform addr -> broadcast
  if (cand > 0 && cand < visible && bval < 0.45f)     // BOUNDARY_COMMIT_THRESHOLD
    cand = max(prev, cand - 1);
  const int commit = max(prev, cand);

  const float sscale = sb / fmaxf(ts, 1e-6f);
  const bool usefb = !(tc > 0.0f);
  const float pscale = pb / fmaxf(tc, 1e-6f);
  const float fbw = pb / fmaxf(tm, 1.0f);

  // ---- pass 2: re-read p,b (cache-warm); outputs + range sums ----
  float* __restrict__ out_speech = out;
  float* __restrict__ out_pause  = out + (size_t)B * UNITS;
  float* __restrict__ out_eff    = out + 2 * (size_t)B * UNITS;

  float eff_rng = 0.f, src_rng = 0.f, eff_tot = 0.f;
#pragma unroll
  for (int c = 0; c < CH; ++c) {
    const int e0 = c * (BLOCK * 4) + 4 * t;
    const float4 p4 = *(const float4*)(pause_weight + base + e0);
    const float4 b4 = *(const float4*)(boundary     + base + e0);
    const float pv[4] = {p4.x, p4.y, p4.z, p4.w};
    const float bv[4] = {b4.x, b4.y, b4.z, b4.w};
    float s_[4], q_[4], e_[4];
#pragma unroll
    for (int j = 0; j < 4; ++j) {
      const int k = c * 4 + j;
      const int idx = e0 + j;
      const float sr = sv_sr[k];
      const float m = (sr != 0.0f) ? 1.0f : 0.0f;     // exact: sr>=1 iff mask==1
      const float sc = fmaxf(pv[j], 0.0f) * (0.5f + bv[j]) * m;
      const float speech = sr * sscale;
      const float pause = usefb ? (m * fbw) : (sc * pscale);
      const float eff = (speech + pause) * m;
      s_[j] = speech;
      q_[j] = pause;
      e_[j] = eff;
      eff_tot += eff;
      const bool inr = (idx >= prev) && (idx < commit);
      eff_rng += inr ? eff : 0.f;
      src_rng += inr ? sv_src[k] : 0.f;
    }
    *reinterpret_cast<float4*>(out_speech + base + e0) =
        make_float4(s_[0], s_[1], s_[2], s_[3]);
    *reinterpret_cast<float4*>(out_pause + base + e0) =
        make_float4(q_[0], q_[1], q_[2], q_[3]);
    *reinterpret_cast<float4*>(out_eff + base + e0) =
        make_float4(e_[0], e_[1], e_[2], e_[3]);
  }

  // ---- wave reduction 2 + per-row scalar outputs ----
  const float execp = bflySum(eff_rng);
  const float srcp = bflySum(src_rng);
  const float etot = bflySum(eff_tot);

  if (t == 0) {
    const bool adv = commit > prev;
    const float nclock = adv ? (cd + (execp - srcp)) : cd;
    const float nback = adv ? fmaxf(nclock, 0.0f) : bl;
    const float vt = fmaxf(etot, 1.0f);
    const float nphase =
        adv ? fminf(fmaxf(pp + execp / vt, 0.0f), 1.0f) : pp;
    const size_t o = 3 * (size_t)B * UNITS;
    out[o + row] = (float)commit;
    out[o + (size_t)B + row] = nphase;
    out[o + 2 * (size_t)B + row] = nback;
    out[o + 3 * (size_t)B + row] = nclock;
  }
}

extern "C" void kernel_launch(void* const* d_in, const int* in_sizes, int n_in,
                              void* d_out, int out_size, void* d_ws, size_t ws_size,
                              hipStream_t stream) {
  const int B = in_sizes[7];  // phase_ptr length
  rhythm_kernel<<<dim3(B), dim3(BLOCK), 0, stream>>>(
      (const float*)d_in[0],   // dur_anchor_src
      (const float*)d_in[1],   // unit_mask
      (const float*)d_in[2],   // speech_budget_win
      (const float*)d_in[3],   // pause_budget_win
      (const float*)d_in[4],   // dur_logratio_unit
      (const float*)d_in[5],   // pause_weight_unit
      (const float*)d_in[6],   // boundary_latent
      (const float*)d_in[7],   // phase_ptr
      (const float*)d_in[8],   // backlog
      (const float*)d_in[9],   // clock_delta
      (const int*)d_in[10],    // commit_frontier
      (const int*)d_in[11],    // open_run_mask
      (float*)d_out, B);
}

// Round 4
// 265.568 us; speedup vs baseline: 1.1104x; 1.1104x over previous
//
#include <hip/hip_runtime.h>
#include <climits>

// StreamingRhythmProjector: B=4096 rows x U=2048 units, one 256-thread block
// (4 waves) per row, 8 elems/thread. Single bulk read pass; register state is
// only sr+sc (16 VGPR) so nothing spills; src range-sum is a tiny L2-warm
// re-read of [prev,commit) (E[len]~10). All lanes compute the scalar epilogue
// (no t0-serial section). Nontemporal stores keep outputs from evicting
// L3-resident inputs.

constexpr int UNITS = 2048;
constexpr int BLOCK = 256;
constexpr int EPT = UNITS / BLOCK;  // 8 elems/thread = 2 float4 chunks

typedef float f32x4 __attribute__((ext_vector_type(4)));

static __device__ __forceinline__ float waveSum(float v) {
#pragma unroll
  for (int m = 1; m < 64; m <<= 1) v += __shfl_xor(v, m, 64);
  return v;  // all lanes hold the sum
}
static __device__ __forceinline__ int waveMin(int v) {
#pragma unroll
  for (int m = 1; m < 64; m <<= 1) v = min(v, __shfl_xor(v, m, 64));
  return v;
}

__global__ __launch_bounds__(BLOCK, 4) void rhythm_kernel(
    const float* __restrict__ dur_anchor,    // [B,U]
    const float* __restrict__ unit_mask,     // [B,U] prefix mask (0/1)
    const float* __restrict__ speech_budget, // [B]
    const float* __restrict__ pause_budget,  // [B]
    const float* __restrict__ dur_logratio,  // [B,U]
    const float* __restrict__ pause_weight,  // [B,U]
    const float* __restrict__ boundary,      // [B,U]
    const float* __restrict__ phase_ptr,     // [B]
    const float* __restrict__ backlog,       // [B]
    const float* __restrict__ clock_delta,   // [B]
    const int*   __restrict__ commit_front,  // [B]
    const int*   __restrict__ open_run,      // [B,U]
    float* __restrict__ out,                 // f32, 3*B*U + 4*B
    int B) {
  const int row = blockIdx.x;
  const int t = threadIdx.x;
  const size_t base = (size_t)row * UNITS;

  // per-row scalars (wave-uniform s_loads, issued before the vector stream)
  const int prev = commit_front[row];
  const float sb = speech_budget[row];
  const float pb = pause_budget[row];
  const float pp = phase_ptr[row];
  const float bl = backlog[row];
  const float cd = clock_delta[row];

  // ---- pass 1: stream all 6 arrays once; state = sr,sc only (16 VGPR) ----
  float sv_sr[EPT];  // masked speech_raw (0 where mask==0, else >= 1)
  float sv_sc[EPT];  // masked pause score
  float sum_sr = 0.f, sum_sc = 0.f, sum_m = 0.f;
  int min_open = INT_MAX;

#pragma unroll
  for (int c = 0; c < EPT / 4; ++c) {
    const int e0 = c * (BLOCK * 4) + 4 * t;
    const float4 a4 = *(const float4*)(dur_anchor   + base + e0);
    const float4 m4 = *(const float4*)(unit_mask    + base + e0);
    const float4 l4 = *(const float4*)(dur_logratio + base + e0);
    const float4 p4 = *(const float4*)(pause_weight + base + e0);
    const float4 b4 = *(const float4*)(boundary     + base + e0);
    const int4   o4 = *(const int4*)(open_run       + base + e0);
    const float av[4] = {a4.x, a4.y, a4.z, a4.w};
    const float mv[4] = {m4.x, m4.y, m4.z, m4.w};
    const float lv[4] = {l4.x, l4.y, l4.z, l4.w};
    const float pv[4] = {p4.x, p4.y, p4.z, p4.w};
    const float bv[4] = {b4.x, b4.y, b4.z, b4.w};
    const int   ov[4] = {o4.x, o4.y, o4.z, o4.w};
#pragma unroll
    for (int j = 0; j < 4; ++j) {
      const int k = c * 4 + j;
      const float m = mv[j];
      const float a = fmaxf(av[j], 1.0f);                      // MIN_SPEECH_FRAMES
      const float bse = a * __expf(lv[j]);
      const float sr = fmaxf(fminf(bse, 3.0f * a), 1.0f) * m;  // MAX_SPEECH_EXPAND
      const float sc = fmaxf(pv[j], 0.0f) * (0.5f + bv[j]) * m;
      sv_sr[k] = sr;
      sv_sc[k] = sc;
      sum_sr += sr;
      sum_sc += sc;
      sum_m += m;
      // prefix mask => (idx < visible) <=> m == 1
      if (ov[j] > 0 && m > 0.5f) min_open = min(min_open, e0 + j);
    }
  }

  // ---- reduction 1: wave butterfly + LDS cross-wave; NO serial section ----
  const int wv = t >> 6, ln = t & 63;
  __shared__ float sf[3][4];
  __shared__ int si[4];
  __shared__ float sg[2][4];  // reused for reduction 2

  const float r0 = waveSum(sum_sr);
  const float r1 = waveSum(sum_sc);
  const float r2 = waveSum(sum_m);
  const int ri = waveMin(min_open);
  if (ln == 0) { sf[0][wv] = r0; sf[1][wv] = r1; sf[2][wv] = r2; si[wv] = ri; }
  __syncthreads();

  // all 256 lanes combine the 4 partials (LDS broadcast) and compute scalars
  const float ts = sf[0][0] + sf[0][1] + sf[0][2] + sf[0][3];
  const float tc = sf[1][0] + sf[1][1] + sf[1][2] + sf[1][3];
  const float tm = sf[2][0] + sf[2][1] + sf[2][2] + sf[2][3];
  const int mo = min(min(si[0], si[1]), min(si[2], si[3]));

  const int visible = (int)(tm + 0.5f);               // exact: integer-valued f32
  const int closed = (mo == INT_MAX) ? visible : mo;
  const int relcap = max(visible - 2, 0);             // TAIL_HOLD_UNITS
  int cand = min(relcap, closed);
  const int bidx = min(max(cand - 1, 0), UNITS - 1);
  const float bval = boundary[base + bidx];           // uniform addr, cache-hot
  if (cand > 0 && cand < visible && bval < 0.45f)     // BOUNDARY_COMMIT_THRESHOLD
    cand = max(prev, cand - 1);
  const int commit = max(prev, cand);

  const float sscale = sb / fmaxf(ts, 1e-6f);
  const bool usefb = !(tc > 0.0f);
  const float pscale = pb / fmaxf(tc, 1e-6f);
  const float fbw = pb / fmaxf(tm, 1.0f);
  // analytic effective total (linearity): Sum eff = sscale*ts + pscale*tc
  const float eff_tot = usefb ? (sscale * ts + fbw * tm) : (sscale * ts + pscale * tc);

  // ---- tiny src range-sum: re-read dur_anchor over [prev,commit) (L2-warm) ----
  float src_rng = 0.f;
  for (int i = prev + t; i < commit; i += BLOCK) src_rng += dur_anchor[base + i];

  // ---- pass 2: outputs from registers (zero bulk re-reads) + eff range sum ----
  float* __restrict__ out_speech = out;
  float* __restrict__ out_pause  = out + (size_t)B * UNITS;
  float* __restrict__ out_eff    = out + 2 * (size_t)B * UNITS;

  float eff_rng = 0.f;
#pragma unroll
  for (int c = 0; c < EPT / 4; ++c) {
    const int e0 = c * (BLOCK * 4) + 4 * t;
    f32x4 s4, q4, e4;
#pragma unroll
    for (int j = 0; j < 4; ++j) {
      const int k = c * 4 + j;
      const int idx = e0 + j;
      const float sr = sv_sr[k];
      const float m = (sr != 0.0f) ? 1.0f : 0.0f;     // exact: sr>=1 iff mask==1
      const float speech = sr * sscale;
      const float pause = usefb ? (m * fbw) : (sv_sc[k] * pscale);
      const float eff = (speech + pause) * m;
      s4[j] = speech;
      q4[j] = pause;
      e4[j] = eff;
      const bool inr = (idx >= prev) && (idx < commit);
      eff_rng += inr ? eff : 0.f;
    }
    __builtin_nontemporal_store(s4, (f32x4*)(out_speech + base + e0));
    __builtin_nontemporal_store(q4, (f32x4*)(out_pause + base + e0));
    __builtin_nontemporal_store(e4, (f32x4*)(out_eff + base + e0));
  }

  // ---- reduction 2: eff_rng, src_rng ----
  const float q0 = waveSum(eff_rng);
  const float q1 = waveSum(src_rng);
  if (ln == 0) { sg[0][wv] = q0; sg[1][wv] = q1; }
  __syncthreads();

  if (t == 0) {
    const float execp = sg[0][0] + sg[0][1] + sg[0][2] + sg[0][3];
    const float srcp  = sg[1][0] + sg[1][1] + sg[1][2] + sg[1][3];
    const bool adv = commit > prev;
    const float nclock = adv ? (cd + (execp - srcp)) : cd;
    const float nback = adv ? fmaxf(nclock, 0.0f) : bl;
    const float vt = fmaxf(eff_tot, 1.0f);
    const float nphase =
        adv ? fminf(fmaxf(pp + execp / vt, 0.0f), 1.0f) : pp;
    const size_t o = 3 * (size_t)B * UNITS;
    out[o + row] = (float)commit;
    out[o + (size_t)B + row] = nphase;
    out[o + 2 * (size_t)B + row] = nback;
    out[o + 3 * (size_t)B + row] = nclock;
  }
}

extern "C" void kernel_launch(void* const* d_in, const int* in_sizes, int n_in,
                              void* d_out, int out_size, void* d_ws, size_t ws_size,
                              hipStream_t stream) {
  const int B = in_sizes[7];  // phase_ptr length
  rhythm_kernel<<<dim3(B), dim3(BLOCK), 0, stream>>>(
      (const float*)d_in[0],   // dur_anchor_src
      (const float*)d_in[1],   // unit_mask
      (const float*)d_in[2],   // speech_budget_win
      (const float*)d_in[3],   // pause_budget_win
      (const float*)d_in[4],   // dur_logratio_unit
      (const float*)d_in[5],   // pause_weight_unit
      (const float*)d_in[6],   // boundary_latent
      (const float*)d_in[7],   // phase_ptr
      (const float*)d_in[8],   // backlog
      (const float*)d_in[9],   // clock_delta
      (const int*)d_in[10],    // commit_frontier
      (const int*)d_in[11],    // open_run_mask
      (float*)d_out, B);
}